// Round 11
// baseline (340.965 us; speedup 1.0000x reference)
//
#include <hip/hip_runtime.h>
#include <hip/hip_bf16.h>
#include <stdint.h>

// Problem dims
#define BB   16
#define SEQ  257
#define DD   1024
#define NH   16
#define HD_  64
#define FF   4096
#define MM   (BB*SEQ)     // 4112 tokens
#define MPAD2 4352
#define SPAD 272
#define VPAD 288
#define SCALE_Q 0.125f

typedef __bf16 bf16x8 __attribute__((ext_vector_type(8)));
typedef float  f32x4  __attribute__((ext_vector_type(4)));
typedef unsigned short u16;

__device__ __forceinline__ u16 f2bf(float f) {
  uint32_t u = __float_as_uint(f);
  uint32_t r = (u + 0x7FFFu + ((u >> 16) & 1u)) >> 16;
  return (u16)r;
}
__device__ __forceinline__ float bf2f(u16 u) {
  return __uint_as_float(((uint32_t)u) << 16);
}
__device__ __forceinline__ void gll16(const void* g, void* l) {
  __builtin_amdgcn_global_load_lds(
      (const __attribute__((address_space(1))) void*)g,
      (__attribute__((address_space(3))) void*)l, 16, 0, 0);
}
__device__ __forceinline__ float wsum(float v) {
  #pragma unroll
  for (int o = 1; o < 64; o <<= 1) v += __shfl_xor(v, o);
  return v;
}

// ------- all weight transposes in ONE launch: fp32 [R][C] -> bf16 [C][R] ---
__global__ __launch_bounds__(256) void transpose_all(
    const float* __restrict__ wq, const float* __restrict__ wk,
    const float* __restrict__ wv, const float* __restrict__ wo,
    const float* __restrict__ w1, const float* __restrict__ w2,
    u16* __restrict__ wqkvT, u16* __restrict__ woT,
    u16* __restrict__ w1T, u16* __restrict__ w2T) {
  __shared__ float tile[64][65];
  const int bid = blockIdx.x;
  const float* src;  u16* dst;  int R, C, b;
  if (bid < 768)       { int s = bid >> 8;  b = bid & 255;
                         src = s==0?wq:(s==1?wk:wv);  dst = wqkvT + s*1024*1024;
                         R = 1024; C = 1024; }
  else if (bid < 1024) { src = wo;  dst = woT;  b = bid - 768;   R = 1024; C = 1024; }
  else if (bid < 2048) { src = w1;  dst = w1T;  b = bid - 1024;  R = 1024; C = 4096; }
  else                 { src = w2;  dst = w2T;  b = bid - 2048;  R = 4096; C = 1024; }
  const int ctiles = C >> 6;
  const int r0 = (b / ctiles) << 6, c0 = (b % ctiles) << 6;
  const int tx = threadIdx.x & 63, ty = threadIdx.x >> 6;
  #pragma unroll
  for (int it = 0; it < 16; ++it) {
    int rr = it * 4 + ty;
    tile[rr][tx] = src[(size_t)(r0 + rr) * C + c0 + tx];
  }
  __syncthreads();
  #pragma unroll
  for (int it = 0; it < 16; ++it) {
    int rr = it * 4 + ty;
    dst[(size_t)(c0 + rr) * R + r0 + tx] = f2bf(tile[tx][rr]);
  }
}

// ---------------- V transpose: vb [bh][SPAD][64] -> vt [bh][64][VPAD] ------
__global__ __launch_bounds__(256) void vtrans_kernel(
    const u16* __restrict__ vb, u16* __restrict__ vt) {
  __shared__ u16 tile[64][72];
  const int bh = blockIdx.x, c = blockIdx.y;
  const int tx = threadIdx.x & 63, ty = threadIdx.x >> 6;
  const u16* src = vb + (size_t)bh * SPAD * HD_;
  u16* dst = vt + (size_t)bh * HD_ * VPAD;
  #pragma unroll
  for (int it = 0; it < 16; ++it) {
    int r = it * 4 + ty;
    int nn = c * 64 + r;  int nnc = nn < SPAD ? nn : SPAD - 1;
    tile[r][tx] = src[(size_t)nnc * HD_ + tx];
  }
  __syncthreads();
  #pragma unroll
  for (int it = 0; it < 16; ++it) {
    int hd = it * 4 + ty;
    int col = c * 64 + tx;
    if (col < VPAD) dst[(size_t)hd * VPAD + col] = tile[tx][hd];
  }
}

// ---------------- LN1 + cosine-sim gate + hidden blend ---------------------
__global__ __launch_bounds__(256) void ln1_gate_kernel(
    const float* __restrict__ h, const float* __restrict__ c,
    const float* __restrict__ g, const float* __restrict__ bta,
    const float* __restrict__ thr, u16* __restrict__ hln,
    float* __restrict__ hblend, float* __restrict__ gate) {
  int m = blockIdx.x, t = threadIdx.x, l = t & 63, w = t >> 6;
  const float4 hv = *(const float4*)(h + (size_t)m * DD + t * 4);
  const float4 cv = *(const float4*)(c + (size_t)m * DD + t * 4);
  float sh = hv.x + hv.y + hv.z + hv.w;
  float sh2 = hv.x*hv.x + hv.y*hv.y + hv.z*hv.z + hv.w*hv.w;
  float sch = hv.x*cv.x + hv.y*cv.y + hv.z*cv.z + hv.w*cv.w;
  float sc2 = cv.x*cv.x + cv.y*cv.y + cv.z*cv.z + cv.w*cv.w;
  sh = wsum(sh); sh2 = wsum(sh2); sch = wsum(sch); sc2 = wsum(sc2);
  __shared__ float red[4][4];
  if (l == 0) { red[w][0]=sh; red[w][1]=sh2; red[w][2]=sch; red[w][3]=sc2; }
  __syncthreads();
  float Sh  = red[0][0]+red[1][0]+red[2][0]+red[3][0];
  float Sh2 = red[0][1]+red[1][1]+red[2][1]+red[3][1];
  float Sch = red[0][2]+red[1][2]+red[2][2]+red[3][2];
  float Sc2 = red[0][3]+red[1][3]+red[2][3]+red[3][3];
  float mean = Sh * (1.f/DD);
  float var  = Sh2 * (1.f/DD) - mean*mean;
  float rs   = rsqrtf(var + 1e-5f);
  float sim  = Sch / (sqrtf(Sc2)*sqrtf(Sh2) + 1e-8f);
  float gv   = 1.f / (1.f + __expf(-(sim - thr[0]) * 4.0f));
  float4 gg = *(const float4*)(g + t*4);
  float4 bb = *(const float4*)(bta + t*4);
  ushort4 ob;
  ob.x = f2bf((hv.x-mean)*rs*gg.x + bb.x);
  ob.y = f2bf((hv.y-mean)*rs*gg.y + bb.y);
  ob.z = f2bf((hv.z-mean)*rs*gg.z + bb.z);
  ob.w = f2bf((hv.w-mean)*rs*gg.w + bb.w);
  *(ushort4*)(hln + (size_t)m * DD + t * 4) = ob;
  float4 hb;
  hb.x = gv*cv.x + (1.f-gv)*hv.x;  hb.y = gv*cv.y + (1.f-gv)*hv.y;
  hb.z = gv*cv.z + (1.f-gv)*hv.z;  hb.w = gv*cv.w + (1.f-gv)*hv.w;
  *(float4*)(hblend + (size_t)m * DD + t * 4) = hb;
  if (t == 0) gate[m] = gv;
}

// ---------------- LN2 -----------------------------------------------------
__global__ __launch_bounds__(256) void ln2_kernel(
    const float* __restrict__ in, const float* __restrict__ g,
    const float* __restrict__ bta, u16* __restrict__ outb) {
  int m = blockIdx.x, t = threadIdx.x, l = t & 63, w = t >> 6;
  const float4 hv = *(const float4*)(in + (size_t)m * DD + t * 4);
  float sh = hv.x + hv.y + hv.z + hv.w;
  float sh2 = hv.x*hv.x + hv.y*hv.y + hv.z*hv.z + hv.w*hv.w;
  sh = wsum(sh); sh2 = wsum(sh2);
  __shared__ float red[4][2];
  if (l == 0) { red[w][0] = sh; red[w][1] = sh2; }
  __syncthreads();
  float Sh  = red[0][0]+red[1][0]+red[2][0]+red[3][0];
  float Sh2 = red[0][1]+red[1][1]+red[2][1]+red[3][1];
  float mean = Sh * (1.f/DD);
  float rs = rsqrtf(Sh2 * (1.f/DD) - mean*mean + 1e-5f);
  float4 gg = *(const float4*)(g + t*4);
  float4 bb = *(const float4*)(bta + t*4);
  ushort4 ob;
  ob.x = f2bf((hv.x-mean)*rs*gg.x + bb.x);
  ob.y = f2bf((hv.y-mean)*rs*gg.y + bb.y);
  ob.z = f2bf((hv.z-mean)*rs*gg.z + bb.z);
  ob.w = f2bf((hv.w-mean)*rs*gg.w + bb.w);
  *(ushort4*)(outb + (size_t)m * DD + t * 4) = ob;
}

// ============ 256x256 8-phase GEMM (m201 template) + VERIFIED T2 swizzle ===
// R3 structure verbatim; ONLY the LDS chunk swizzle added (both-sides,
// rule #21, 0-conflict verified R7/R9/R10 on the same [rows][32] geometry):
//   write: linear gll16 dest + source logical chunk = (tid&3)^((tid>>3)&3)
//   read:  chunk = lh ^ ((lr>>1)&3)   (per-lane constant)
#define VMW4 do { asm volatile("s_waitcnt vmcnt(4)" ::: "memory"); \
                  __builtin_amdgcn_sched_barrier(0); } while(0)
#define VMW0 do { asm volatile("s_waitcnt vmcnt(0)" ::: "memory"); \
                  __builtin_amdgcn_sched_barrier(0); } while(0)

#define STG_A(T_, KS_, SLOT_) do { \
  const u16* _g = pA + (T_)*64 + (KS_)*32; \
  gll16(_g, &sA[SLOT_][KS_][0] + tid*8); \
  gll16(_g + rowStep, &sA[SLOT_][KS_][0] + 4096 + tid*8); } while(0)
#define STG_B(T_, KS_, SLOT_) do { \
  const u16* _g = pB + (T_)*64 + (KS_)*32; \
  gll16(_g, &sB[SLOT_][KS_][0] + tid*8); \
  gll16(_g + rowStep, &sB[SLOT_][KS_][0] + 4096 + tid*8); } while(0)

#define PHASE(SLOT_, KS_, MH_, RB_, STG_STMT, VM_STMT) do { \
  { const u16* _pa = &sA[SLOT_][KS_][aBase + (MH_)*2048]; \
    av[0] = *(const bf16x8*)(_pa);      av[1] = *(const bf16x8*)(_pa+512); \
    av[2] = *(const bf16x8*)(_pa+1024); av[3] = *(const bf16x8*)(_pa+1536); } \
  if (RB_) { const u16* _pb = &sB[SLOT_][KS_][bBase]; \
    fv[0] = *(const bf16x8*)(_pb);      fv[1] = *(const bf16x8*)(_pb+512); \
    fv[2] = *(const bf16x8*)(_pb+1024); fv[3] = *(const bf16x8*)(_pb+1536); } \
  STG_STMT; \
  __builtin_amdgcn_s_barrier(); \
  asm volatile("s_waitcnt lgkmcnt(0)" ::: "memory"); \
  __builtin_amdgcn_sched_barrier(0); \
  __builtin_amdgcn_s_setprio(1); \
  _Pragma("unroll") \
  for (int f = 0; f < 4; ++f) \
    _Pragma("unroll") \
    for (int n = 0; n < 4; ++n) \
      acc[(MH_)*4+f][n] = __builtin_amdgcn_mfma_f32_16x16x32_bf16( \
          av[f], fv[n], acc[(MH_)*4+f][n], 0, 0, 0); \
  __builtin_amdgcn_s_setprio(0); \
  VM_STMT; \
  __builtin_amdgcn_s_barrier(); } while(0)

template<int EPI, int KT>
__global__ __launch_bounds__(512, 2) void gemm256(
    const u16* __restrict__ A, const u16* __restrict__ Bt,
    int Kstride, int kBase0,
    const float* __restrict__ bias,
    const float* __restrict__ gate,
    const float* __restrict__ c0, const float* __restrict__ c1, const float* __restrict__ c2,
    const float* __restrict__ bq, const float* __restrict__ bk, const float* __restrict__ bvp,
    u16* __restrict__ qb, u16* __restrict__ kb, u16* __restrict__ vb,
    u16* __restrict__ outb, u16* __restrict__ partb) {
  const int tid = threadIdx.x, w = tid >> 6, l = tid & 63, lr = l & 15, lh = l >> 4;
  const int wm = w >> 2, wn = w & 3;
  const int n0 = blockIdx.x * 256, m0 = blockIdx.y * 256;
  const int kBase = kBase0 + blockIdx.z * (KT * 64);

  __shared__ u16 sA[2][2][8192];   // [slot][kslice][256 rows * 32 k] = 64KB
  __shared__ u16 sB[2][2][8192];   // 64KB

  f32x4 acc[8][4];
  f32x4 zero = {0.f, 0.f, 0.f, 0.f};
  #pragma unroll
  for (int i = 0; i < 8; ++i)
    #pragma unroll
    for (int j = 0; j < 4; ++j) acc[i][j] = zero;

  // staging: thread covers rows (tid>>2), (tid>>2)+128; phys chunk tid&3;
  // SOURCE logical chunk = (tid&3) ^ s(row), s(row)=(row>>1)&3=((tid>>3)&3)
  const int rS = tid >> 2;
  const int cS = ((tid & 3) ^ ((tid >> 3) & 3)) * 8;
  const u16* pA = A  + (size_t)(m0 + rS) * Kstride + kBase + cS;
  const u16* pB = Bt + (size_t)(n0 + rS) * Kstride + kBase + cS;
  const size_t rowStep = (size_t)128 * Kstride;

  // fragment read bases: chunk = lh ^ s(row), s(row)=(lr>>1)&3 (row==lr mod 16)
  const int cx = ((lh ^ ((lr >> 1) & 3)) & 3) * 8;
  const int aBase = (wm*128 + lr) * 32 + cx;
  const int bBase = (wn*64  + lr) * 32 + cx;
  bf16x8 av[4], fv[4];

  // ---- prologue: t0 fully, t1 k0 ----
  STG_A(0,0,0);  STG_B(0,0,0);
  STG_A(0,1,0);  STG_B(0,1,0);
  STG_A(1,0,1);  STG_B(1,0,1);
  asm volatile("s_waitcnt vmcnt(4)" ::: "memory");
  __builtin_amdgcn_sched_barrier(0);
  __builtin_amdgcn_s_barrier();

  // ---- main loop: iter computes tiles (2i, 2i+1); stages per schedule ----
  #pragma unroll 1
  for (int i = 0; i < KT/2 - 1; ++i) {
    const int jB = 2*i+1, nA = 2*i+2, nB = 2*i+3;
    PHASE(0,0,0,1, STG_A(jB,1,1), ((void)0));
    PHASE(0,0,1,0, STG_B(jB,1,1), ((void)0));
    PHASE(0,1,0,1, STG_A(nA,0,0), ((void)0));
    PHASE(0,1,1,0, STG_B(nA,0,0), VMW4);
    PHASE(1,0,0,1, STG_A(nA,1,0), ((void)0));
    PHASE(1,0,1,0, STG_B(nA,1,0), ((void)0));
    PHASE(1,1,0,1, STG_A(nB,0,1), ((void)0));
    PHASE(1,1,1,0, STG_B(nB,0,1), VMW4);
  }
  // ---- tail iter ----
  PHASE(0,0,0,1, STG_A(KT-1,1,1), ((void)0));
  PHASE(0,0,1,0, STG_B(KT-1,1,1), ((void)0));
  PHASE(0,1,0,1, ((void)0), ((void)0));
  PHASE(0,1,1,0, ((void)0), VMW0);
  PHASE(1,0,0,1, ((void)0), ((void)0));
  PHASE(1,0,1,0, ((void)0), ((void)0));
  PHASE(1,1,0,1, ((void)0), ((void)0));
  PHASE(1,1,1,0, ((void)0), ((void)0));

  // ---- epilogue ----
  const int crow = m0 + wm*128, ccol = n0 + wn*64;
  if constexpr (EPI == 0) {
    const int which = n0 >> 10;
    const float* cb = which==0 ? bq : (which==1 ? bk : bvp);
    const float* cp = which==0 ? c0 : (which==1 ? c1 : c2);
    u16* dst = which==0 ? qb : (which==1 ? kb : vb);
    const float scl = which==0 ? SCALE_Q : 1.0f;
    #pragma unroll
    for (int mi = 0; mi < 8; ++mi)
      #pragma unroll
      for (int rr = 0; rr < 4; ++rr) {
        const int row = crow + mi*16 + lh*4 + rr;
        if (row < MM) {
          const float gv = gate[row];
          const int bidx = row / SEQ, nn = row - bidx * SEQ;
          #pragma unroll
          for (int ni = 0; ni < 4; ++ni) {
            const int col = ccol + ni*16 + lr;
            const int d = col & 1023, hd = d & 63, hh = d >> 6;
            const float lin = acc[mi][ni][rr] + cb[d];
            const float val = (gv * cp[(size_t)row*DD + d] + (1.f - gv) * lin) * scl;
            dst[((size_t)(bidx*NH + hh)*SPAD + nn)*HD_ + hd] = f2bf(val);
          }
        }
      }
  } else if constexpr (EPI == 2) {
    #pragma unroll
    for (int mi = 0; mi < 8; ++mi)
      #pragma unroll
      for (int rr = 0; rr < 4; ++rr) {
        const int row = crow + mi*16 + lh*4 + rr;
        if (row < MM) {
          #pragma unroll
          for (int ni = 0; ni < 4; ++ni) {
            const int col = ccol + ni*16 + lr;
            const float x = acc[mi][ni][rr] + bias[col];
            const float s = 1.f / (1.f + __expf(-1.702f * x));
            outb[(size_t)row*FF + col] = f2bf(x * s);
          }
        }
      }
  } else {  // EPI == 3: bf16 partial, stride 1024
    u16* pp = partb + (size_t)blockIdx.z * ((size_t)MPAD2 * 1024);
    #pragma unroll
    for (int mi = 0; mi < 8; ++mi)
      #pragma unroll
      for (int rr = 0; rr < 4; ++rr) {
        const int row = crow + mi*16 + lh*4 + rr;
        if (row < MM) {
          #pragma unroll
          for (int ni = 0; ni < 4; ++ni) {
            const int col = ccol + ni*16 + lr;
            pp[(size_t)row*1024 + col] = f2bf(acc[mi][ni][rr]);
          }
        }
      }
  }
}

// ------- 128^2 3-slot GEMM (R7-proven) for O-proj: out = A@Bt + bias + add -
template<int EPI>
__global__ __launch_bounds__(256, 3) void gemm_bt(
    const u16* __restrict__ A, const u16* __restrict__ Bt,
    int Kstride, int Kiter,
    const float* __restrict__ bias,
    const float* __restrict__ addsrc, float* __restrict__ outf) {
  const int tid = threadIdx.x, w = tid >> 6, l = tid & 63, lr = l & 15, lh = l >> 4;
  const int Mt = gridDim.x;
  const int f = blockIdx.y * Mt + blockIdx.x;
  const int nwg = Mt * gridDim.y;
  const int q8 = nwg >> 3, r8 = nwg & 7, xcd = f & 7, lin = f >> 3;
  const int swz = (xcd < r8 ? xcd * (q8 + 1) : r8 * (q8 + 1) + (xcd - r8) * q8) + lin;
  const int m0 = (swz % Mt) * 128, n0 = (swz / Mt) * 128;
  const int wm = w >> 1, wn = w & 1;
  __shared__ u16 sA[3][4096], sB[3][4096];
  f32x4 acc[4][4];
  f32x4 zero = {0.f, 0.f, 0.f, 0.f};
  #pragma unroll
  for (int i = 0; i < 4; ++i)
    #pragma unroll
    for (int j = 0; j < 4; ++j) acc[i][j] = zero;

  const int rS = tid >> 2;
  const int srcC = (((tid & 3) ^ ((tid >> 3) & 3)) * 8);
  const u16* gA = A  + (size_t)(m0 + rS) * Kstride + srcC;
  const u16* gB = Bt + (size_t)(n0 + rS) * Kstride + srcC;
  const size_t rStep = (size_t)64 * Kstride;

  const int sL = (lr >> 1) & 3;
  const int coff = ((lh ^ sL) & 3) * 8;
  const int rdA = (wm*64 + lr) * 32 + coff;
  const int rdB = (wn*64 + lr) * 32 + coff;

  #define STAGE(S_, T_) do { \
    const int _ko = (T_) << 5; \
    gll16(gA + _ko,         &sA[S_][0]    + tid*8); \
    gll16(gA + _ko + rStep, &sA[S_][2048] + tid*8); \
    gll16(gB + _ko,         &sB[S_][0]    + tid*8); \
    gll16(gB + _ko + rStep, &sB[S_][2048] + tid*8); \
  } while(0)

  const int nt = Kiter >> 5;
  STAGE(0, 0);
  STAGE(1, 1);
  #pragma unroll 1
  for (int t = 0; t < nt; ++t) {
    const int sc = t % 3;
    __builtin_amdgcn_s_barrier();
    if (t + 2 < nt) {
      STAGE((t + 2) % 3, t + 2);
      asm volatile("s_waitcnt vmcnt(8)" ::: "memory");
    } else if (t + 1 < nt) {
      asm volatile("s_waitcnt vmcnt(4)" ::: "memory");
    } else {
      asm volatile("s_waitcnt vmcnt(0)" ::: "memory");
    }
    __builtin_amdgcn_sched_barrier(0);
    __builtin_amdgcn_s_barrier();
    __builtin_amdgcn_sched_barrier(0);
    bf16x8 af[4], bfr[4];
    #pragma unroll
    for (int mi = 0; mi < 4; ++mi)
      af[mi] = *(const bf16x8*)&sA[sc][rdA + mi*512];
    #pragma unroll
    for (int ni = 0; ni < 4; ++ni)
      bfr[ni] = *(const bf16x8*)&sB[sc][rdB + ni*512];
    #pragma unroll
    for (int mi = 0; mi < 4; ++mi)
      #pragma unroll
      for (int ni = 0; ni < 4; ++ni)
        acc[mi][ni] = __builtin_amdgcn_mfma_f32_16x16x32_bf16(af[mi], bfr[ni], acc[mi][ni], 0, 0, 0);
  }
  #undef STAGE

  #pragma unroll
  for (int mi = 0; mi < 4; ++mi)
    #pragma unroll
    for (int r = 0; r < 4; ++r) {
      const int row = m0 + wm*64 + mi*16 + lh*4 + r;
      if (row < MM) {
        #pragma unroll
        for (int ni = 0; ni < 4; ++ni) {
          const int col = n0 + wn*64 + ni*16 + lr;
          outf[(size_t)row*DD + col] = acc[mi][ni][r] + bias[col] + addsrc[(size_t)row*DD + col];
        }
      }
    }
}

// ------- MLP2 reduce: out = p0..p3 + bias + resid2 (fp32 out) --------------
__global__ __launch_bounds__(256) void reduce_mlp2(
    const u16* __restrict__ parts, const float* __restrict__ bias,
    const float* __restrict__ resid, float* __restrict__ out) {
  const size_t PS = (size_t)MPAD2 * 1024;
  const int row = blockIdx.x, t = threadIdx.x, c = t * 4;
  const size_t base = (size_t)row * 1024 + c;
  float4 r = *(const float4*)(resid + base);
  float4 b = *(const float4*)(bias + c);
  float o0 = r.x + b.x, o1 = r.y + b.y, o2 = r.z + b.z, o3 = r.w + b.w;
  #pragma unroll
  for (int p = 0; p < 4; ++p) {
    ushort4 u = *(const ushort4*)(parts + p*PS + base);
    o0 += bf2f(u.x);  o1 += bf2f(u.y);  o2 += bf2f(u.z);  o3 += bf2f(u.w);
  }
  float4 o;  o.x = o0;  o.y = o1;  o.z = o2;  o.w = o3;
  *(float4*)(out + base) = o;
}

// ---------------- attention: one (b,h) x 64-qrow tile per block ------------
__global__ __launch_bounds__(256) void attn_kernel(
    const u16* __restrict__ qb, const u16* __restrict__ kb,
    const u16* __restrict__ vt, u16* __restrict__ attn_out) {
  __shared__ u16 P[64 * 296];
  const int bh = blockIdx.x, b = bh >> 4, hh = bh & 15;
  const int q0 = blockIdx.y * 64;
  const int tid = threadIdx.x, w = tid >> 6, l = tid & 63, lr = l & 15, lh = l >> 4;
  const u16* qp = qb + (size_t)bh * SPAD * HD_;
  const u16* kp = kb + (size_t)bh * SPAD * HD_;
  const u16* vp = vt + (size_t)bh * HD_ * VPAD;

  const int qr = q0 + w*16 + lr;
  const int qrc = qr < 271 ? qr : 271;
  bf16x8 aq0 = *(const bf16x8*)(qp + (size_t)qrc*HD_ + lh*8);
  bf16x8 aq1 = *(const bf16x8*)(qp + (size_t)qrc*HD_ + 32 + lh*8);

  f32x4 st[18];
  f32x4 zero = {0.f,0.f,0.f,0.f};
  #pragma unroll
  for (int t = 0; t < 18; ++t) st[t] = zero;
  #pragma unroll
  for (int t = 0; t < 18; ++t) {
    int key = t*16 + lr;  int keyc = key < 271 ? key : 271;
    bf16x8 b0 = *(const bf16x8*)(kp + (size_t)keyc*HD_ + lh*8);
    bf16x8 b1 = *(const bf16x8*)(kp + (size_t)keyc*HD_ + 32 + lh*8);
    st[t] = __builtin_amdgcn_mfma_f32_16x16x32_bf16(aq0, b0, st[t], 0, 0, 0);
    st[t] = __builtin_amdgcn_mfma_f32_16x16x32_bf16(aq1, b1, st[t], 0, 0, 0);
  }
  #pragma unroll
  for (int t = 0; t < 18; ++t) {
    int key = t*16 + lr;
    if (key >= SEQ) { st[t][0]=-1e30f; st[t][1]=-1e30f; st[t][2]=-1e30f; st[t][3]=-1e30f; }
  }
  float mr[4], sr[4];
  #pragma unroll
  for (int r = 0; r < 4; ++r) {
    float m = st[0][r];
    #pragma unroll
    for (int t = 1; t < 18; ++t) m = fmaxf(m, st[t][r]);
    m = fmaxf(m, __shfl_xor(m, 1));  m = fmaxf(m, __shfl_xor(m, 2));
    m = fmaxf(m, __shfl_xor(m, 4));  m = fmaxf(m, __shfl_xor(m, 8));
    mr[r] = m;  sr[r] = 0.f;
  }
  #pragma unroll
  for (int t = 0; t < 18; ++t)
    #pragma unroll
    for (int r = 0; r < 4; ++r) {
      float p = __expf(st[t][r] - mr[r]);
      st[t][r] = p;  sr[r] += p;
    }
  #pragma unroll
  for (int r = 0; r < 4; ++r) {
    sr[r] += __shfl_xor(sr[r], 1);  sr[r] += __shfl_xor(sr[r], 2);
    sr[r] += __shfl_xor(sr[r], 4);  sr[r] += __shfl_xor(sr[r], 8);
  }
  #pragma unroll
  for (int t = 0; t < 18; ++t)
    #pragma unroll
    for (int r = 0; r < 4; ++r)
      P[(w*16 + lh*4 + r)*296 + t*16 + lr] = f2bf(st[t][r]);
  __syncthreads();

  f32x4 o[4];
  #pragma unroll
  for (int ni = 0; ni < 4; ++ni) o[ni] = zero;
  #pragma unroll
  for (int ks = 0; ks < 9; ++ks) {
    bf16x8 pa = *(const bf16x8*)&P[(w*16 + lr)*296 + ks*32 + lh*8];
    #pragma unroll
    for (int ni = 0; ni < 4; ++ni) {
      bf16x8 bv_ = *(const bf16x8*)(vp + (size_t)(ni*16 + lr)*VPAD + ks*32 + lh*8);
      o[ni] = __builtin_amdgcn_mfma_f32_16x16x32_bf16(pa, bv_, o[ni], 0, 0, 0);
    }
  }
  #pragma unroll
  for (int r = 0; r < 4; ++r) {
    const int qrow = q0 + w*16 + lh*4 + r;
    if (qrow < SEQ) {
      const float inv = 1.f / sr[r];
      #pragma unroll
      for (int ni = 0; ni < 4; ++ni)
        attn_out[(size_t)(b*SEQ + qrow)*DD + hh*HD_ + ni*16 + lr] = f2bf(o[ni][r] * inv);
    }
  }
}

// ---------------- host ----------------------------------------------------
extern "C" void kernel_launch(void* const* d_in, const int* in_sizes, int n_in,
                              void* d_out, int out_size, void* d_ws, size_t ws_size,
                              hipStream_t stream) {
  (void)in_sizes; (void)n_in; (void)out_size; (void)ws_size;
  const float* hidden   = (const float*)d_in[0];
  const float* cached_h = (const float*)d_in[1];
  const float* cached_q = (const float*)d_in[2];
  const float* cached_k = (const float*)d_in[3];
  const float* cached_v = (const float*)d_in[4];
  const float* ln1_g = (const float*)d_in[5];
  const float* ln1_b = (const float*)d_in[6];
  const float* wq = (const float*)d_in[7];
  const float* bq = (const float*)d_in[8];
  const float* wk = (const float*)d_in[9];
  const float* bk = (const float*)d_in[10];
  const float* wv = (const float*)d_in[11];
  const float* bv = (const float*)d_in[12];
  const float* wo = (const float*)d_in[13];
  const float* bo = (const float*)d_in[14];
  const float* ln2_g = (const float*)d_in[15];
  const float* ln2_b = (const float*)d_in[16];
  const float* w1 = (const float*)d_in[17];
  const float* b1 = (const float*)d_in[18];
  const float* w2 = (const float*)d_in[19];
  const float* b2 = (const float*)d_in[20];
  const float* thr = (const float*)d_in[21];
  float* out = (float*)d_out;

  char* ws = (char*)d_ws;
  size_t off = 0;
  auto alloc = [&](size_t bytes) {
    void* p = ws + off;  off += (bytes + 255) & ~(size_t)255;  return p;
  };
  u16*   wqkvT  = (u16*)alloc(3072ull * 1024 * 2);
  u16*   woT    = (u16*)alloc(1024ull * 1024 * 2);
  u16*   w1T    = (u16*)alloc(4096ull * 1024 * 2);
  u16*   w2T    = (u16*)alloc(1024ull * 4096 * 2);
  float* gate   = (float*)alloc((size_t)MPAD2 * 4);
  float* resid2 = (float*)alloc((size_t)MPAD2 * DD * 4);
  u16*   regA   = (u16*)alloc((size_t)MPAD2 * DD * 2);
  u16 *hln = regA, *attn_o = regA, *ln2out = regA;
  // region B overlays:
  //  [0..): qbuf kbuf vbuf vtb  -> mid (after attn)
  //  [partsOff..): hblend (LN1 -> O-proj) -> mlp2 bf16 partials x4
  const size_t QKV_B  = (size_t)256 * SPAD * HD_ * 2;
  const size_t VT_B   = (size_t)256 * HD_ * VPAD * 2;
  const size_t PART_B = (size_t)MPAD2 * 1024 * 2;
  const size_t partsOff = 3*QKV_B + VT_B;
  char*  regB   = (char*)alloc(partsOff + 4*PART_B);
  u16*   qbuf   = (u16*)regB;
  u16*   kbuf   = (u16*)(regB + QKV_B);
  u16*   vbuf   = (u16*)(regB + 2*QKV_B);
  u16*   vtb    = (u16*)(regB + 3*QKV_B);
  float* hblend = (float*)(regB + partsOff);
  u16*   mid    = (u16*)regB;
  u16*   parts  = (u16*)(regB + partsOff);

  dim3 blk(256), blk5(512);
  transpose_all<<<dim3(3072), blk, 0, stream>>>(wq, wk, wv, wo, w1, w2,
                                                wqkvT, woT, w1T, w2T);

  ln1_gate_kernel<<<dim3(MM), blk, 0, stream>>>(hidden, cached_h, ln1_g, ln1_b, thr,
                                                hln, hblend, gate);

  // QKV: 256^2 8-phase, grid (n=12, m=17); fused blend epilogue
  gemm256<0,16><<<dim3(12, 17), blk5, 0, stream>>>(hln, wqkvT, 1024, 0,
      nullptr, gate, cached_q, cached_k, cached_v, bq, bk, bv,
      qbuf, kbuf, vbuf, nullptr, nullptr);

  vtrans_kernel<<<dim3(256, 5), blk, 0, stream>>>(vbuf, vtb);
  attn_kernel<<<dim3(256, 5), blk, 0, stream>>>(qbuf, kbuf, vtb, attn_o);

  // O-proj (128^2 3-slot): resid2 = attn@woT + bo + hblend
  gemm_bt<1><<<dim3(33, 8), blk, 0, stream>>>(attn_o, woT, 1024, 1024, bo,
      hblend, resid2);

  ln2_kernel<<<dim3(MM), blk, 0, stream>>>(resid2, ln2_g, ln2_b, ln2out);

  // MLP1: 256^2 8-phase, grid (16,17): gelu(ln2out @ w1T + b1) -> mid
  gemm256<2,16><<<dim3(16, 17), blk5, 0, stream>>>(ln2out, w1T, 1024, 0,
      b1, nullptr, nullptr, nullptr, nullptr, nullptr, nullptr, nullptr,
      nullptr, nullptr, nullptr, mid, nullptr);

  // MLP2: 256^2 8-phase split-K=4, grid (4,17,4): bf16 partials
  gemm256<3,16><<<dim3(4, 17, 4), blk5, 0, stream>>>(mid, w2T, 4096, 0,
      nullptr, nullptr, nullptr, nullptr, nullptr, nullptr, nullptr, nullptr,
      nullptr, nullptr, nullptr, nullptr, parts);

  reduce_mlp2<<<dim3(MM), blk, 0, stream>>>(parts, b2, resid2, out);
}

// Round 12
// 309.905 us; speedup vs baseline: 1.1002x; 1.1002x over previous
//
#include <hip/hip_runtime.h>
#include <hip/hip_bf16.h>
#include <stdint.h>

// Problem dims
#define BB   16
#define SEQ  257
#define DD   1024
#define NH   16
#define HD_  64
#define FF   4096
#define MM   (BB*SEQ)     // 4112 tokens
#define MPAD2 4352
#define SPAD 272
#define VPAD 288
#define SCALE_Q 0.125f

typedef __bf16 bf16x8 __attribute__((ext_vector_type(8)));
typedef float  f32x4  __attribute__((ext_vector_type(4)));
typedef unsigned short u16;

__device__ __forceinline__ u16 f2bf(float f) {
  uint32_t u = __float_as_uint(f);
  uint32_t r = (u + 0x7FFFu + ((u >> 16) & 1u)) >> 16;
  return (u16)r;
}
__device__ __forceinline__ float bf2f(u16 u) {
  return __uint_as_float(((uint32_t)u) << 16);
}
__device__ __forceinline__ void gll16(const void* g, void* l) {
  __builtin_amdgcn_global_load_lds(
      (const __attribute__((address_space(1))) void*)g,
      (__attribute__((address_space(3))) void*)l, 16, 0, 0);
}
__device__ __forceinline__ float wsum(float v) {
  #pragma unroll
  for (int o = 1; o < 64; o <<= 1) v += __shfl_xor(v, o);
  return v;
}

// ---- fused prologue: weight transposes (bid<3072) + LN1/gate (bid>=3072) --
// Bodies verbatim from the previously-verified transpose_all / ln1_gate.
__global__ __launch_bounds__(256) void prologue_kernel(
    const float* __restrict__ wq, const float* __restrict__ wk,
    const float* __restrict__ wv, const float* __restrict__ wo,
    const float* __restrict__ w1, const float* __restrict__ w2,
    u16* __restrict__ wqkvT, u16* __restrict__ woT,
    u16* __restrict__ w1T, u16* __restrict__ w2T,
    const float* __restrict__ h, const float* __restrict__ c,
    const float* __restrict__ g, const float* __restrict__ bta,
    const float* __restrict__ thr, u16* __restrict__ hln,
    float* __restrict__ hblend, float* __restrict__ gate) {
  __shared__ float tile[64][65];
  __shared__ float red[4][4];
  const int bid = blockIdx.x;
  if (bid < 3072) {
    const float* src;  u16* dst;  int R, C, b;
    if (bid < 768)       { int s = bid >> 8;  b = bid & 255;
                           src = s==0?wq:(s==1?wk:wv);  dst = wqkvT + s*1024*1024;
                           R = 1024; C = 1024; }
    else if (bid < 1024) { src = wo;  dst = woT;  b = bid - 768;   R = 1024; C = 1024; }
    else if (bid < 2048) { src = w1;  dst = w1T;  b = bid - 1024;  R = 1024; C = 4096; }
    else                 { src = w2;  dst = w2T;  b = bid - 2048;  R = 4096; C = 1024; }
    const int ctiles = C >> 6;
    const int r0 = (b / ctiles) << 6, c0 = (b % ctiles) << 6;
    const int tx = threadIdx.x & 63, ty = threadIdx.x >> 6;
    #pragma unroll
    for (int it = 0; it < 16; ++it) {
      int rr = it * 4 + ty;
      tile[rr][tx] = src[(size_t)(r0 + rr) * C + c0 + tx];
    }
    __syncthreads();
    #pragma unroll
    for (int it = 0; it < 16; ++it) {
      int rr = it * 4 + ty;
      dst[(size_t)(c0 + rr) * R + r0 + tx] = f2bf(tile[tx][rr]);
    }
  } else {
    const int m = bid - 3072;
    const int t = threadIdx.x, l = t & 63, w = t >> 6;
    const float4 hv = *(const float4*)(h + (size_t)m * DD + t * 4);
    const float4 cv = *(const float4*)(c + (size_t)m * DD + t * 4);
    float sh = hv.x + hv.y + hv.z + hv.w;
    float sh2 = hv.x*hv.x + hv.y*hv.y + hv.z*hv.z + hv.w*hv.w;
    float sch = hv.x*cv.x + hv.y*cv.y + hv.z*cv.z + hv.w*cv.w;
    float sc2 = cv.x*cv.x + cv.y*cv.y + cv.z*cv.z + cv.w*cv.w;
    sh = wsum(sh); sh2 = wsum(sh2); sch = wsum(sch); sc2 = wsum(sc2);
    if (l == 0) { red[w][0]=sh; red[w][1]=sh2; red[w][2]=sch; red[w][3]=sc2; }
    __syncthreads();
    float Sh  = red[0][0]+red[1][0]+red[2][0]+red[3][0];
    float Sh2 = red[0][1]+red[1][1]+red[2][1]+red[3][1];
    float Sch = red[0][2]+red[1][2]+red[2][2]+red[3][2];
    float Sc2 = red[0][3]+red[1][3]+red[2][3]+red[3][3];
    float mean = Sh * (1.f/DD);
    float var  = Sh2 * (1.f/DD) - mean*mean;
    float rs   = rsqrtf(var + 1e-5f);
    float sim  = Sch / (sqrtf(Sc2)*sqrtf(Sh2) + 1e-8f);
    float gv   = 1.f / (1.f + __expf(-(sim - thr[0]) * 4.0f));
    float4 gg = *(const float4*)(g + t*4);
    float4 bb = *(const float4*)(bta + t*4);
    ushort4 ob;
    ob.x = f2bf((hv.x-mean)*rs*gg.x + bb.x);
    ob.y = f2bf((hv.y-mean)*rs*gg.y + bb.y);
    ob.z = f2bf((hv.z-mean)*rs*gg.z + bb.z);
    ob.w = f2bf((hv.w-mean)*rs*gg.w + bb.w);
    *(ushort4*)(hln + (size_t)m * DD + t * 4) = ob;
    float4 hb;
    hb.x = gv*cv.x + (1.f-gv)*hv.x;  hb.y = gv*cv.y + (1.f-gv)*hv.y;
    hb.z = gv*cv.z + (1.f-gv)*hv.z;  hb.w = gv*cv.w + (1.f-gv)*hv.w;
    *(float4*)(hblend + (size_t)m * DD + t * 4) = hb;
    if (t == 0) gate[m] = gv;
  }
}

// ---------------- V transpose: vb [bh][SPAD][64] -> vt [bh][64][VPAD] ------
__global__ __launch_bounds__(256) void vtrans_kernel(
    const u16* __restrict__ vb, u16* __restrict__ vt) {
  __shared__ u16 tile[64][72];
  const int bh = blockIdx.x, c = blockIdx.y;
  const int tx = threadIdx.x & 63, ty = threadIdx.x >> 6;
  const u16* src = vb + (size_t)bh * SPAD * HD_;
  u16* dst = vt + (size_t)bh * HD_ * VPAD;
  #pragma unroll
  for (int it = 0; it < 16; ++it) {
    int r = it * 4 + ty;
    int nn = c * 64 + r;  int nnc = nn < SPAD ? nn : SPAD - 1;
    tile[r][tx] = src[(size_t)nnc * HD_ + tx];
  }
  __syncthreads();
  #pragma unroll
  for (int it = 0; it < 16; ++it) {
    int hd = it * 4 + ty;
    int col = c * 64 + tx;
    if (col < VPAD) dst[(size_t)hd * VPAD + col] = tile[tx][hd];
  }
}

// ---------------- LN2 -----------------------------------------------------
__global__ __launch_bounds__(256) void ln2_kernel(
    const float* __restrict__ in, const float* __restrict__ g,
    const float* __restrict__ bta, u16* __restrict__ outb) {
  int m = blockIdx.x, t = threadIdx.x, l = t & 63, w = t >> 6;
  const float4 hv = *(const float4*)(in + (size_t)m * DD + t * 4);
  float sh = hv.x + hv.y + hv.z + hv.w;
  float sh2 = hv.x*hv.x + hv.y*hv.y + hv.z*hv.z + hv.w*hv.w;
  sh = wsum(sh); sh2 = wsum(sh2);
  __shared__ float red[4][2];
  if (l == 0) { red[w][0] = sh; red[w][1] = sh2; }
  __syncthreads();
  float Sh  = red[0][0]+red[1][0]+red[2][0]+red[3][0];
  float Sh2 = red[0][1]+red[1][1]+red[2][1]+red[3][1];
  float mean = Sh * (1.f/DD);
  float rs = rsqrtf(Sh2 * (1.f/DD) - mean*mean + 1e-5f);
  float4 gg = *(const float4*)(g + t*4);
  float4 bb = *(const float4*)(bta + t*4);
  ushort4 ob;
  ob.x = f2bf((hv.x-mean)*rs*gg.x + bb.x);
  ob.y = f2bf((hv.y-mean)*rs*gg.y + bb.y);
  ob.z = f2bf((hv.z-mean)*rs*gg.z + bb.z);
  ob.w = f2bf((hv.w-mean)*rs*gg.w + bb.w);
  *(ushort4*)(outb + (size_t)m * DD + t * 4) = ob;
}

// ---------------- GEMM: C = A[M,K](bf16) x Bt[N,K]^T(bf16) -----------------
// R7-proven best: 2-phase prefetch, double-buffered LDS, BK=64, tile layout
// [128][64] (row stride 128B) with G4 bank swizzle (0 conflicts verified):
// phys 16B-chunk = logical ^ (row&7); write = linear gll16 dest + inverse-
// permuted GLOBAL source chunk; read = per-lane constant XOR.
// + XCD-chunked block swizzle (all grids %8==0), grid x=m (fast), y=n.
template<int EPI>
__global__ __launch_bounds__(256) void gemm_bt(
    const u16* __restrict__ A, const u16* __restrict__ Bt,
    int Kstride, int Kiter,
    const float* __restrict__ bias,
    const float* __restrict__ gate,
    const float* __restrict__ c0, const float* __restrict__ c1, const float* __restrict__ c2,
    const float* __restrict__ bq, const float* __restrict__ bk, const float* __restrict__ bv,
    u16* __restrict__ qb, u16* __restrict__ kb, u16* __restrict__ vb,
    const float* __restrict__ addsrc, float* __restrict__ outf,
    u16* __restrict__ outb, u16* __restrict__ partb) {
  const int tid = threadIdx.x, w = tid >> 6, l = tid & 63, lr = l & 15, lh = l >> 4;
  // XCD-chunked swizzle (nwg divisible by 8 for all our grids)
  const int Mt = gridDim.x;
  const int f = blockIdx.y * Mt + blockIdx.x;
  const int nwg = Mt * gridDim.y;
  const int swz = (f & 7) * (nwg >> 3) + (f >> 3);
  const int m0 = (swz % Mt) * 128, n0 = (swz / Mt) * 128;
  const int kBase = blockIdx.z * Kiter;
  const int wm = w >> 1, wn = w & 1;
  __shared__ u16 sA[2][8192], sB[2][8192];   // [buf][128 rows * 64 k] = 64KB
  f32x4 acc[4][4];
  f32x4 zero = {0.f, 0.f, 0.f, 0.f};
  #pragma unroll
  for (int i = 0; i < 4; ++i)
    #pragma unroll
    for (int j = 0; j < 4; ++j) acc[i][j] = zero;

  // staging: call j covers rows 32j + (tid>>3); phys chunk = tid&7;
  // source logical chunk = phys ^ (row&7)  (inverse of the read swizzle)
  const int rS = tid >> 3;                         // 0..31
  const int srcC = ((tid & 7) ^ (rS & 7)) * 8;     // u16 offset within 64-k row
  const u16* gA = A  + (size_t)(m0 + rS) * Kstride + kBase + srcC;
  const u16* gB = Bt + (size_t)(n0 + rS) * Kstride + kBase + srcC;
  const size_t rStep = (size_t)32 * Kstride;

  // read bases: row stride 64 u16; chunk = ((ks*4+lh) ^ (lr&7)) * 8 u16.
  const int rdA = (wm*64 + lr) * 64;
  const int rdB = (wn*64 + lr) * 64;
  const int cx0 = ((lh ^ (lr & 7)) & 7) * 8;       // ks=0 chunk offset (u16)

  #define STAGE(BUF_, T_) do { \
    const int _ko = (T_) * 64; \
    _Pragma("unroll") \
    for (int _j = 0; _j < 4; ++_j) { \
      gll16(gA + _ko + _j*rStep, &sA[BUF_][_j*2048] + tid*8); \
      gll16(gB + _ko + _j*rStep, &sB[BUF_][_j*2048] + tid*8); \
    } } while(0)

  const int nt = Kiter >> 6;
  STAGE(0, 0);
  for (int t = 0; t < nt; ++t) {
    const int cur = t & 1;
    __syncthreads();
    if (t + 1 < nt) STAGE(cur ^ 1, t + 1);
    #pragma unroll
    for (int ks = 0; ks < 2; ++ks) {
      const int co = cx0 ^ (ks * 32);
      bf16x8 af[4], bfr[4];
      #pragma unroll
      for (int mi = 0; mi < 4; ++mi)
        af[mi] = *(const bf16x8*)&sA[cur][rdA + mi*1024 + co];
      #pragma unroll
      for (int ni = 0; ni < 4; ++ni)
        bfr[ni] = *(const bf16x8*)&sB[cur][rdB + ni*1024 + co];
      #pragma unroll
      for (int mi = 0; mi < 4; ++mi)
        #pragma unroll
        for (int ni = 0; ni < 4; ++ni)
          acc[mi][ni] = __builtin_amdgcn_mfma_f32_16x16x32_bf16(af[mi], bfr[ni], acc[mi][ni], 0, 0, 0);
    }
  }
  #undef STAGE

  if constexpr (EPI == 0) {
    const int which = n0 >> 10;
    const float* cb = which==0 ? bq : (which==1 ? bk : bv);
    const float* cp = which==0 ? c0 : (which==1 ? c1 : c2);
    u16* dst = which==0 ? qb : (which==1 ? kb : vb);
    const float scl = which==0 ? SCALE_Q : 1.0f;
    #pragma unroll
    for (int mi = 0; mi < 4; ++mi) {
      #pragma unroll
      for (int r = 0; r < 4; ++r) {
        const int row = m0 + wm*64 + mi*16 + lh*4 + r;
        if (row < MM) {
          const float gv = gate[row];
          const int bidx = row / SEQ, nn = row - bidx * SEQ;
          #pragma unroll
          for (int ni = 0; ni < 4; ++ni) {
            const int col = n0 + wn*64 + ni*16 + lr;
            const int d = col & 1023, hd = d & 63, hh = d >> 6;
            const float lin = acc[mi][ni][r] + cb[d];
            const float val = (gv * cp[(size_t)row*DD + d] + (1.f - gv) * lin) * scl;
            dst[((size_t)(bidx*NH + hh)*SPAD + nn)*HD_ + hd] = f2bf(val);
          }
        }
      }
    }
  } else if constexpr (EPI == 1) {
    #pragma unroll
    for (int mi = 0; mi < 4; ++mi)
      #pragma unroll
      for (int r = 0; r < 4; ++r) {
        const int row = m0 + wm*64 + mi*16 + lh*4 + r;
        if (row < MM) {
          #pragma unroll
          for (int ni = 0; ni < 4; ++ni) {
            const int col = n0 + wn*64 + ni*16 + lr;
            outf[(size_t)row*DD + col] = acc[mi][ni][r] + bias[col] + addsrc[(size_t)row*DD + col];
          }
        }
      }
  } else if constexpr (EPI == 2) {
    #pragma unroll
    for (int mi = 0; mi < 4; ++mi)
      #pragma unroll
      for (int r = 0; r < 4; ++r) {
        const int row = m0 + wm*64 + mi*16 + lh*4 + r;
        if (row < MM) {
          #pragma unroll
          for (int ni = 0; ni < 4; ++ni) {
            const int col = n0 + wn*64 + ni*16 + lr;
            const float x = acc[mi][ni][r] + bias[col];
            const float s = 1.f / (1.f + __expf(-1.702f * x));
            outb[(size_t)row*FF + col] = f2bf(x * s);
          }
        }
      }
  } else {  // EPI == 3: bf16 partial, stride 1024, z-sliced
    u16* pp = partb + (size_t)blockIdx.z * ((size_t)MPAD2 * 1024);
    #pragma unroll
    for (int mi = 0; mi < 4; ++mi)
      #pragma unroll
      for (int r = 0; r < 4; ++r) {
        const int row = m0 + wm*64 + mi*16 + lh*4 + r;
        if (row < MM) {
          #pragma unroll
          for (int ni = 0; ni < 4; ++ni) {
            const int col = n0 + wn*64 + ni*16 + lr;
            pp[(size_t)row*1024 + col] = f2bf(acc[mi][ni][r]);
          }
        }
      }
  }
}

// ---------------- MLP2 reduce: out = part0 + part1 + bias + resid ----------
__global__ __launch_bounds__(256) void reduce_mlp2(
    const u16* __restrict__ parts, const float* __restrict__ bias,
    const float* __restrict__ resid, float* __restrict__ out) {
  const size_t PS = (size_t)MPAD2 * 1024;
  const int row = blockIdx.x, t = threadIdx.x, c = t * 4;
  const size_t base = (size_t)row * 1024 + c;
  float4 r = *(const float4*)(resid + base);
  float4 b = *(const float4*)(bias + c);
  float o0 = r.x + b.x, o1 = r.y + b.y, o2 = r.z + b.z, o3 = r.w + b.w;
  #pragma unroll
  for (int p = 0; p < 2; ++p) {
    ushort4 u = *(const ushort4*)(parts + p*PS + base);
    o0 += bf2f(u.x);  o1 += bf2f(u.y);  o2 += bf2f(u.z);  o3 += bf2f(u.w);
  }
  float4 o;  o.x = o0;  o.y = o1;  o.z = o2;  o.w = o3;
  *(float4*)(out + base) = o;
}

// ---------------- attention: one (b,h) x 64-qrow tile per block ------------
__global__ __launch_bounds__(256) void attn_kernel(
    const u16* __restrict__ qb, const u16* __restrict__ kb,
    const u16* __restrict__ vt, u16* __restrict__ attn_out) {
  __shared__ u16 P[64 * 296];
  const int bh = blockIdx.x, b = bh >> 4, hh = bh & 15;
  const int q0 = blockIdx.y * 64;
  const int tid = threadIdx.x, w = tid >> 6, l = tid & 63, lr = l & 15, lh = l >> 4;
  const u16* qp = qb + (size_t)bh * SPAD * HD_;
  const u16* kp = kb + (size_t)bh * SPAD * HD_;
  const u16* vp = vt + (size_t)bh * HD_ * VPAD;

  const int qr = q0 + w*16 + lr;
  const int qrc = qr < 271 ? qr : 271;
  bf16x8 aq0 = *(const bf16x8*)(qp + (size_t)qrc*HD_ + lh*8);
  bf16x8 aq1 = *(const bf16x8*)(qp + (size_t)qrc*HD_ + 32 + lh*8);

  f32x4 st[18];
  f32x4 zero = {0.f,0.f,0.f,0.f};
  #pragma unroll
  for (int t = 0; t < 18; ++t) st[t] = zero;
  #pragma unroll
  for (int t = 0; t < 18; ++t) {
    int key = t*16 + lr;  int keyc = key < 271 ? key : 271;
    bf16x8 b0 = *(const bf16x8*)(kp + (size_t)keyc*HD_ + lh*8);
    bf16x8 b1 = *(const bf16x8*)(kp + (size_t)keyc*HD_ + 32 + lh*8);
    st[t] = __builtin_amdgcn_mfma_f32_16x16x32_bf16(aq0, b0, st[t], 0, 0, 0);
    st[t] = __builtin_amdgcn_mfma_f32_16x16x32_bf16(aq1, b1, st[t], 0, 0, 0);
  }
  #pragma unroll
  for (int t = 0; t < 18; ++t) {
    int key = t*16 + lr;
    if (key >= SEQ) { st[t][0]=-1e30f; st[t][1]=-1e30f; st[t][2]=-1e30f; st[t][3]=-1e30f; }
  }
  float mr[4], sr[4];
  #pragma unroll
  for (int r = 0; r < 4; ++r) {
    float m = st[0][r];
    #pragma unroll
    for (int t = 1; t < 18; ++t) m = fmaxf(m, st[t][r]);
    m = fmaxf(m, __shfl_xor(m, 1));  m = fmaxf(m, __shfl_xor(m, 2));
    m = fmaxf(m, __shfl_xor(m, 4));  m = fmaxf(m, __shfl_xor(m, 8));
    mr[r] = m;  sr[r] = 0.f;
  }
  #pragma unroll
  for (int t = 0; t < 18; ++t)
    #pragma unroll
    for (int r = 0; r < 4; ++r) {
      float p = __expf(st[t][r] - mr[r]);
      st[t][r] = p;  sr[r] += p;
    }
  #pragma unroll
  for (int r = 0; r < 4; ++r) {
    sr[r] += __shfl_xor(sr[r], 1);  sr[r] += __shfl_xor(sr[r], 2);
    sr[r] += __shfl_xor(sr[r], 4);  sr[r] += __shfl_xor(sr[r], 8);
  }
  #pragma unroll
  for (int t = 0; t < 18; ++t)
    #pragma unroll
    for (int r = 0; r < 4; ++r)
      P[(w*16 + lh*4 + r)*296 + t*16 + lr] = f2bf(st[t][r]);
  __syncthreads();

  f32x4 o[4];
  #pragma unroll
  for (int ni = 0; ni < 4; ++ni) o[ni] = zero;
  #pragma unroll
  for (int ks = 0; ks < 9; ++ks) {
    bf16x8 pa = *(const bf16x8*)&P[(w*16 + lr)*296 + ks*32 + lh*8];
    #pragma unroll
    for (int ni = 0; ni < 4; ++ni) {
      bf16x8 bv_ = *(const bf16x8*)(vp + (size_t)(ni*16 + lr)*VPAD + ks*32 + lh*8);
      o[ni] = __builtin_amdgcn_mfma_f32_16x16x32_bf16(pa, bv_, o[ni], 0, 0, 0);
    }
  }
  #pragma unroll
  for (int r = 0; r < 4; ++r) {
    const int qrow = q0 + w*16 + lh*4 + r;
    if (qrow < SEQ) {
      const float inv = 1.f / sr[r];
      #pragma unroll
      for (int ni = 0; ni < 4; ++ni)
        attn_out[(size_t)(b*SEQ + qrow)*DD + hh*HD_ + ni*16 + lr] = f2bf(o[ni][r] * inv);
    }
  }
}

// ---------------- host ----------------------------------------------------
extern "C" void kernel_launch(void* const* d_in, const int* in_sizes, int n_in,
                              void* d_out, int out_size, void* d_ws, size_t ws_size,
                              hipStream_t stream) {
  (void)in_sizes; (void)n_in; (void)out_size; (void)ws_size;
  const float* hidden   = (const float*)d_in[0];
  const float* cached_h = (const float*)d_in[1];
  const float* cached_q = (const float*)d_in[2];
  const float* cached_k = (const float*)d_in[3];
  const float* cached_v = (const float*)d_in[4];
  const float* ln1_g = (const float*)d_in[5];
  const float* ln1_b = (const float*)d_in[6];
  const float* wq = (const float*)d_in[7];
  const float* bq = (const float*)d_in[8];
  const float* wk = (const float*)d_in[9];
  const float* bk = (const float*)d_in[10];
  const float* wv = (const float*)d_in[11];
  const float* bv = (const float*)d_in[12];
  const float* wo = (const float*)d_in[13];
  const float* bo = (const float*)d_in[14];
  const float* ln2_g = (const float*)d_in[15];
  const float* ln2_b = (const float*)d_in[16];
  const float* w1 = (const float*)d_in[17];
  const float* b1 = (const float*)d_in[18];
  const float* w2 = (const float*)d_in[19];
  const float* b2 = (const float*)d_in[20];
  const float* thr = (const float*)d_in[21];
  float* out = (float*)d_out;

  char* ws = (char*)d_ws;
  size_t off = 0;
  auto alloc = [&](size_t bytes) {
    void* p = ws + off;  off += (bytes + 255) & ~(size_t)255;  return p;
  };
  u16*   wqkvT  = (u16*)alloc(3072ull * 1024 * 2);
  u16*   woT    = (u16*)alloc(1024ull * 1024 * 2);
  u16*   w1T    = (u16*)alloc(4096ull * 1024 * 2);
  u16*   w2T    = (u16*)alloc(1024ull * 4096 * 2);
  float* gate   = (float*)alloc((size_t)MPAD2 * 4);
  float* resid2 = (float*)alloc((size_t)MPAD2 * DD * 4);
  u16*   regA   = (u16*)alloc((size_t)MPAD2 * DD * 2);
  u16 *hln = regA, *attn_o = regA, *ln2out = regA;
  const size_t QKV_B  = (size_t)256 * SPAD * HD_ * 2;
  const size_t VT_B   = (size_t)256 * HD_ * VPAD * 2;
  const size_t PART_B = (size_t)MPAD2 * 1024 * 2;
  const size_t partsOff = 3*QKV_B + VT_B;
  char*  regB   = (char*)alloc(partsOff + 2*PART_B);
  u16*   qbuf   = (u16*)regB;
  u16*   kbuf   = (u16*)(regB + QKV_B);
  u16*   vbuf   = (u16*)(regB + 2*QKV_B);
  u16*   vtb    = (u16*)(regB + 3*QKV_B);
  float* hblend = (float*)(regB + partsOff);
  u16*   mid    = (u16*)regB;
  u16*   parts  = (u16*)(regB + partsOff);

  dim3 blk(256);
  // fused prologue: 3072 transpose blocks + 4112 LN1/gate blocks
  prologue_kernel<<<dim3(3072 + MM), blk, 0, stream>>>(
      wq, wk, wv, wo, w1, w2, wqkvT, woT, w1T, w2T,
      hidden, cached_h, ln1_g, ln1_b, thr, hln, hblend, gate);

  // QKV: grid x=m(33), y=n(24); fused blend epilogue
  gemm_bt<0><<<dim3(33, 24), blk, 0, stream>>>(hln, wqkvT, 1024, 1024, nullptr,
      gate, cached_q, cached_k, cached_v, bq, bk, bv, qbuf, kbuf, vbuf,
      nullptr, nullptr, nullptr, nullptr);

  vtrans_kernel<<<dim3(256, 5), blk, 0, stream>>>(vbuf, vtb);
  attn_kernel<<<dim3(256, 5), blk, 0, stream>>>(qbuf, kbuf, vtb, attn_o);

  // O-proj: resid2 = attn@woT + bo + hblend
  gemm_bt<1><<<dim3(33, 8), blk, 0, stream>>>(attn_o, woT, 1024, 1024, bo,
      nullptr, nullptr, nullptr, nullptr, nullptr, nullptr, nullptr,
      nullptr, nullptr, nullptr, hblend, resid2, nullptr, nullptr);

  ln2_kernel<<<dim3(MM), blk, 0, stream>>>(resid2, ln2_g, ln2_b, ln2out);

  // MLP1: gelu(ln2out @ w1T + b1) -> mid
  gemm_bt<2><<<dim3(33, 32), blk, 0, stream>>>(ln2out, w1T, 1024, 1024, b1,
      nullptr, nullptr, nullptr, nullptr, nullptr, nullptr, nullptr,
      nullptr, nullptr, nullptr, nullptr, nullptr, mid, nullptr);

  // MLP2 split-K=2 (z: kBase = z*2048): bf16 partials
  gemm_bt<3><<<dim3(33, 8, 2), blk, 0, stream>>>(mid, w2T, 4096, 2048, nullptr,
      nullptr, nullptr, nullptr, nullptr, nullptr, nullptr, nullptr,
      nullptr, nullptr, nullptr, nullptr, nullptr, nullptr, parts);

  reduce_mlp2<<<dim3(MM), blk, 0, stream>>>(parts, b2, resid2, out);
}

// Round 13
// 306.307 us; speedup vs baseline: 1.1131x; 1.0117x over previous
//
#include <hip/hip_runtime.h>
#include <hip/hip_bf16.h>
#include <stdint.h>

// Problem dims
#define BB   16
#define SEQ  257
#define DD   1024
#define NH   16
#define HD_  64
#define FF   4096
#define MM   (BB*SEQ)     // 4112 tokens
#define MPAD2 4352
#define SPAD 272
#define VPAD 288
#define SCALE_Q 0.125f

typedef __bf16 bf16x8 __attribute__((ext_vector_type(8)));
typedef float  f32x4  __attribute__((ext_vector_type(4)));
typedef unsigned short u16;

__device__ __forceinline__ u16 f2bf(float f) {
  uint32_t u = __float_as_uint(f);
  uint32_t r = (u + 0x7FFFu + ((u >> 16) & 1u)) >> 16;
  return (u16)r;
}
__device__ __forceinline__ float bf2f(u16 u) {
  return __uint_as_float(((uint32_t)u) << 16);
}
__device__ __forceinline__ void gll16(const void* g, void* l) {
  __builtin_amdgcn_global_load_lds(
      (const __attribute__((address_space(1))) void*)g,
      (__attribute__((address_space(3))) void*)l, 16, 0, 0);
}
__device__ __forceinline__ float wsum(float v) {
  #pragma unroll
  for (int o = 1; o < 64; o <<= 1) v += __shfl_xor(v, o);
  return v;
}

// ---- fused prologue: weight transposes (bid<3072) + LN1/gate (bid>=3072) --
__global__ __launch_bounds__(256) void prologue_kernel(
    const float* __restrict__ wq, const float* __restrict__ wk,
    const float* __restrict__ wv, const float* __restrict__ wo,
    const float* __restrict__ w1, const float* __restrict__ w2,
    u16* __restrict__ wqkvT, u16* __restrict__ woT,
    u16* __restrict__ w1T, u16* __restrict__ w2T,
    const float* __restrict__ h, const float* __restrict__ c,
    const float* __restrict__ g, const float* __restrict__ bta,
    const float* __restrict__ thr, u16* __restrict__ hln,
    float* __restrict__ hblend, float* __restrict__ gate) {
  __shared__ float tile[64][65];
  __shared__ float red[4][4];
  const int bid = blockIdx.x;
  if (bid < 3072) {
    const float* src;  u16* dst;  int R, C, b;
    if (bid < 768)       { int s = bid >> 8;  b = bid & 255;
                           src = s==0?wq:(s==1?wk:wv);  dst = wqkvT + s*1024*1024;
                           R = 1024; C = 1024; }
    else if (bid < 1024) { src = wo;  dst = woT;  b = bid - 768;   R = 1024; C = 1024; }
    else if (bid < 2048) { src = w1;  dst = w1T;  b = bid - 1024;  R = 1024; C = 4096; }
    else                 { src = w2;  dst = w2T;  b = bid - 2048;  R = 4096; C = 1024; }
    const int ctiles = C >> 6;
    const int r0 = (b / ctiles) << 6, c0 = (b % ctiles) << 6;
    const int tx = threadIdx.x & 63, ty = threadIdx.x >> 6;
    #pragma unroll
    for (int it = 0; it < 16; ++it) {
      int rr = it * 4 + ty;
      tile[rr][tx] = src[(size_t)(r0 + rr) * C + c0 + tx];
    }
    __syncthreads();
    #pragma unroll
    for (int it = 0; it < 16; ++it) {
      int rr = it * 4 + ty;
      dst[(size_t)(c0 + rr) * R + r0 + tx] = f2bf(tile[tx][rr]);
    }
  } else {
    const int m = bid - 3072;
    const int t = threadIdx.x, l = t & 63, w = t >> 6;
    const float4 hv = *(const float4*)(h + (size_t)m * DD + t * 4);
    const float4 cv = *(const float4*)(c + (size_t)m * DD + t * 4);
    float sh = hv.x + hv.y + hv.z + hv.w;
    float sh2 = hv.x*hv.x + hv.y*hv.y + hv.z*hv.z + hv.w*hv.w;
    float sch = hv.x*cv.x + hv.y*cv.y + hv.z*cv.z + hv.w*cv.w;
    float sc2 = cv.x*cv.x + cv.y*cv.y + cv.z*cv.z + cv.w*cv.w;
    sh = wsum(sh); sh2 = wsum(sh2); sch = wsum(sch); sc2 = wsum(sc2);
    if (l == 0) { red[w][0]=sh; red[w][1]=sh2; red[w][2]=sch; red[w][3]=sc2; }
    __syncthreads();
    float Sh  = red[0][0]+red[1][0]+red[2][0]+red[3][0];
    float Sh2 = red[0][1]+red[1][1]+red[2][1]+red[3][1];
    float Sch = red[0][2]+red[1][2]+red[2][2]+red[3][2];
    float Sc2 = red[0][3]+red[1][3]+red[2][3]+red[3][3];
    float mean = Sh * (1.f/DD);
    float var  = Sh2 * (1.f/DD) - mean*mean;
    float rs   = rsqrtf(var + 1e-5f);
    float sim  = Sch / (sqrtf(Sc2)*sqrtf(Sh2) + 1e-8f);
    float gv   = 1.f / (1.f + __expf(-(sim - thr[0]) * 4.0f));
    float4 gg = *(const float4*)(g + t*4);
    float4 bb = *(const float4*)(bta + t*4);
    ushort4 ob;
    ob.x = f2bf((hv.x-mean)*rs*gg.x + bb.x);
    ob.y = f2bf((hv.y-mean)*rs*gg.y + bb.y);
    ob.z = f2bf((hv.z-mean)*rs*gg.z + bb.z);
    ob.w = f2bf((hv.w-mean)*rs*gg.w + bb.w);
    *(ushort4*)(hln + (size_t)m * DD + t * 4) = ob;
    float4 hb;
    hb.x = gv*cv.x + (1.f-gv)*hv.x;  hb.y = gv*cv.y + (1.f-gv)*hv.y;
    hb.z = gv*cv.z + (1.f-gv)*hv.z;  hb.w = gv*cv.w + (1.f-gv)*hv.w;
    *(float4*)(hblend + (size_t)m * DD + t * 4) = hb;
    if (t == 0) gate[m] = gv;
  }
}

// ---------------- V transpose: vb [bh][SPAD][64] -> vt [bh][64][VPAD] ------
__global__ __launch_bounds__(256) void vtrans_kernel(
    const u16* __restrict__ vb, u16* __restrict__ vt) {
  __shared__ u16 tile[64][72];
  const int bh = blockIdx.x, c = blockIdx.y;
  const int tx = threadIdx.x & 63, ty = threadIdx.x >> 6;
  const u16* src = vb + (size_t)bh * SPAD * HD_;
  u16* dst = vt + (size_t)bh * HD_ * VPAD;
  #pragma unroll
  for (int it = 0; it < 16; ++it) {
    int r = it * 4 + ty;
    int nn = c * 64 + r;  int nnc = nn < SPAD ? nn : SPAD - 1;
    tile[r][tx] = src[(size_t)nnc * HD_ + tx];
  }
  __syncthreads();
  #pragma unroll
  for (int it = 0; it < 16; ++it) {
    int hd = it * 4 + ty;
    int col = c * 64 + tx;
    if (col < VPAD) dst[(size_t)hd * VPAD + col] = tile[tx][hd];
  }
}

// ---------------- LN2 -----------------------------------------------------
__global__ __launch_bounds__(256) void ln2_kernel(
    const float* __restrict__ in, const float* __restrict__ g,
    const float* __restrict__ bta, u16* __restrict__ outb) {
  int m = blockIdx.x, t = threadIdx.x, l = t & 63, w = t >> 6;
  const float4 hv = *(const float4*)(in + (size_t)m * DD + t * 4);
  float sh = hv.x + hv.y + hv.z + hv.w;
  float sh2 = hv.x*hv.x + hv.y*hv.y + hv.z*hv.z + hv.w*hv.w;
  sh = wsum(sh); sh2 = wsum(sh2);
  __shared__ float red[4][2];
  if (l == 0) { red[w][0] = sh; red[w][1] = sh2; }
  __syncthreads();
  float Sh  = red[0][0]+red[1][0]+red[2][0]+red[3][0];
  float Sh2 = red[0][1]+red[1][1]+red[2][1]+red[3][1];
  float mean = Sh * (1.f/DD);
  float rs = rsqrtf(Sh2 * (1.f/DD) - mean*mean + 1e-5f);
  float4 gg = *(const float4*)(g + t*4);
  float4 bb = *(const float4*)(bta + t*4);
  ushort4 ob;
  ob.x = f2bf((hv.x-mean)*rs*gg.x + bb.x);
  ob.y = f2bf((hv.y-mean)*rs*gg.y + bb.y);
  ob.z = f2bf((hv.z-mean)*rs*gg.z + bb.z);
  ob.w = f2bf((hv.w-mean)*rs*gg.w + bb.w);
  *(ushort4*)(outb + (size_t)m * DD + t * 4) = ob;
}

// ---------------- GEMM: C = A[M,K](bf16) x Bt[N,K]^T(bf16) -----------------
// Clean TLP test: 128x128, BK=32, 2 LDS slots = 32KB (LDS cap 5 blocks/CU),
// NO forced waves-per-EU bound (R10's 48-VGPR squeeze was the confound).
// Verified 0-conflict [128][32] swizzle: phys chunk = logical ^ ((row>>1)&3);
// write = linear gll16 dest + inverse-permuted global source chunk;
// read = per-lane constant XOR. XCD-chunked swizzle (grids %8), z=split-K.
template<int EPI>
__global__ __launch_bounds__(256) void gemm_bt(
    const u16* __restrict__ A, const u16* __restrict__ Bt,
    int Kstride, int Kiter,
    const float* __restrict__ bias,
    const float* __restrict__ gate,
    const float* __restrict__ c0, const float* __restrict__ c1, const float* __restrict__ c2,
    const float* __restrict__ bq, const float* __restrict__ bk, const float* __restrict__ bv,
    u16* __restrict__ qb, u16* __restrict__ kb, u16* __restrict__ vb,
    const float* __restrict__ addsrc, float* __restrict__ outf,
    u16* __restrict__ outb, u16* __restrict__ partb) {
  const int tid = threadIdx.x, w = tid >> 6, l = tid & 63, lr = l & 15, lh = l >> 4;
  const int Mt = gridDim.x;
  const int f = blockIdx.y * Mt + blockIdx.x;
  const int nwg = Mt * gridDim.y;
  const int swz = (f & 7) * (nwg >> 3) + (f >> 3);
  const int m0 = (swz % Mt) * 128, n0 = (swz / Mt) * 128;
  const int kBase = blockIdx.z * Kiter;
  const int wm = w >> 1, wn = w & 1;
  __shared__ u16 sA[2][4096], sB[2][4096];   // 2 slots x [128][32] = 32KB
  f32x4 acc[4][4];
  f32x4 zero = {0.f, 0.f, 0.f, 0.f};
  #pragma unroll
  for (int i = 0; i < 4; ++i)
    #pragma unroll
    for (int j = 0; j < 4; ++j) acc[i][j] = zero;

  const int rS = tid >> 2;
  const int srcC = (((tid & 3) ^ ((tid >> 3) & 3)) * 8);
  const u16* gA = A  + (size_t)(m0 + rS) * Kstride + kBase + srcC;
  const u16* gB = Bt + (size_t)(n0 + rS) * Kstride + kBase + srcC;
  const size_t rStep = (size_t)64 * Kstride;

  const int sL = (lr >> 1) & 3;
  const int coff = ((lh ^ sL) & 3) * 8;
  const int rdA = (wm*64 + lr) * 32 + coff;
  const int rdB = (wn*64 + lr) * 32 + coff;

  #define STAGE(S_, T_) do { \
    const int _ko = (T_) << 5; \
    gll16(gA + _ko,         &sA[S_][0]    + tid*8); \
    gll16(gA + _ko + rStep, &sA[S_][2048] + tid*8); \
    gll16(gB + _ko,         &sB[S_][0]    + tid*8); \
    gll16(gB + _ko + rStep, &sB[S_][2048] + tid*8); \
  } while(0)

  const int nt = Kiter >> 5;
  STAGE(0, 0);
  #pragma unroll 1
  for (int t = 0; t < nt; ++t) {
    const int cur = t & 1;
    __syncthreads();
    if (t + 1 < nt) STAGE(cur ^ 1, t + 1);
    bf16x8 af[4], bfr[4];
    #pragma unroll
    for (int mi = 0; mi < 4; ++mi)
      af[mi] = *(const bf16x8*)&sA[cur][rdA + mi*512];
    #pragma unroll
    for (int ni = 0; ni < 4; ++ni)
      bfr[ni] = *(const bf16x8*)&sB[cur][rdB + ni*512];
    #pragma unroll
    for (int mi = 0; mi < 4; ++mi)
      #pragma unroll
      for (int ni = 0; ni < 4; ++ni)
        acc[mi][ni] = __builtin_amdgcn_mfma_f32_16x16x32_bf16(af[mi], bfr[ni], acc[mi][ni], 0, 0, 0);
  }
  #undef STAGE

  if constexpr (EPI == 0) {
    const int which = n0 >> 10;
    const float* cb = which==0 ? bq : (which==1 ? bk : bv);
    const float* cp = which==0 ? c0 : (which==1 ? c1 : c2);
    u16* dst = which==0 ? qb : (which==1 ? kb : vb);
    const float scl = which==0 ? SCALE_Q : 1.0f;
    #pragma unroll
    for (int mi = 0; mi < 4; ++mi) {
      #pragma unroll
      for (int r = 0; r < 4; ++r) {
        const int row = m0 + wm*64 + mi*16 + lh*4 + r;
        if (row < MM) {
          const float gv = gate[row];
          const int bidx = row / SEQ, nn = row - bidx * SEQ;
          #pragma unroll
          for (int ni = 0; ni < 4; ++ni) {
            const int col = n0 + wn*64 + ni*16 + lr;
            const int d = col & 1023, hd = d & 63, hh = d >> 6;
            const float lin2 = acc[mi][ni][r] + cb[d];
            const float val = (gv * cp[(size_t)row*DD + d] + (1.f - gv) * lin2) * scl;
            dst[((size_t)(bidx*NH + hh)*SPAD + nn)*HD_ + hd] = f2bf(val);
          }
        }
      }
    }
  } else if constexpr (EPI == 1) {
    #pragma unroll
    for (int mi = 0; mi < 4; ++mi)
      #pragma unroll
      for (int r = 0; r < 4; ++r) {
        const int row = m0 + wm*64 + mi*16 + lh*4 + r;
        if (row < MM) {
          #pragma unroll
          for (int ni = 0; ni < 4; ++ni) {
            const int col = n0 + wn*64 + ni*16 + lr;
            outf[(size_t)row*DD + col] = acc[mi][ni][r] + bias[col] + addsrc[(size_t)row*DD + col];
          }
        }
      }
  } else if constexpr (EPI == 2) {
    #pragma unroll
    for (int mi = 0; mi < 4; ++mi)
      #pragma unroll
      for (int r = 0; r < 4; ++r) {
        const int row = m0 + wm*64 + mi*16 + lh*4 + r;
        if (row < MM) {
          #pragma unroll
          for (int ni = 0; ni < 4; ++ni) {
            const int col = n0 + wn*64 + ni*16 + lr;
            const float x = acc[mi][ni][r] + bias[col];
            const float s = 1.f / (1.f + __expf(-1.702f * x));
            outb[(size_t)row*FF + col] = f2bf(x * s);
          }
        }
      }
  } else {  // EPI == 3: bf16 partial, stride 1024, z-sliced
    u16* pp = partb + (size_t)blockIdx.z * ((size_t)MPAD2 * 1024);
    #pragma unroll
    for (int mi = 0; mi < 4; ++mi)
      #pragma unroll
      for (int r = 0; r < 4; ++r) {
        const int row = m0 + wm*64 + mi*16 + lh*4 + r;
        if (row < MM) {
          #pragma unroll
          for (int ni = 0; ni < 4; ++ni) {
            const int col = n0 + wn*64 + ni*16 + lr;
            pp[(size_t)row*1024 + col] = f2bf(acc[mi][ni][r]);
          }
        }
      }
  }
}

// ---------------- MLP2 reduce: out = part0 + part1 + bias + resid ----------
__global__ __launch_bounds__(256) void reduce_mlp2(
    const u16* __restrict__ parts, const float* __restrict__ bias,
    const float* __restrict__ resid, float* __restrict__ out) {
  const size_t PS = (size_t)MPAD2 * 1024;
  const int row = blockIdx.x, t = threadIdx.x, c = t * 4;
  const size_t base = (size_t)row * 1024 + c;
  float4 r = *(const float4*)(resid + base);
  float4 b = *(const float4*)(bias + c);
  float o0 = r.x + b.x, o1 = r.y + b.y, o2 = r.z + b.z, o3 = r.w + b.w;
  #pragma unroll
  for (int p = 0; p < 2; ++p) {
    ushort4 u = *(const ushort4*)(parts + p*PS + base);
    o0 += bf2f(u.x);  o1 += bf2f(u.y);  o2 += bf2f(u.z);  o3 += bf2f(u.w);
  }
  float4 o;  o.x = o0;  o.y = o1;  o.z = o2;  o.w = o3;
  *(float4*)(out + base) = o;
}

// ---------------- attention: one (b,h) x 64-qrow tile per block ------------
__global__ __launch_bounds__(256) void attn_kernel(
    const u16* __restrict__ qb, const u16* __restrict__ kb,
    const u16* __restrict__ vt, u16* __restrict__ attn_out) {
  __shared__ u16 P[64 * 296];
  const int bh = blockIdx.x, b = bh >> 4, hh = bh & 15;
  const int q0 = blockIdx.y * 64;
  const int tid = threadIdx.x, w = tid >> 6, l = tid & 63, lr = l & 15, lh = l >> 4;
  const u16* qp = qb + (size_t)bh * SPAD * HD_;
  const u16* kp = kb + (size_t)bh * SPAD * HD_;
  const u16* vp = vt + (size_t)bh * HD_ * VPAD;

  const int qr = q0 + w*16 + lr;
  const int qrc = qr < 271 ? qr : 271;
  bf16x8 aq0 = *(const bf16x8*)(qp + (size_t)qrc*HD_ + lh*8);
  bf16x8 aq1 = *(const bf16x8*)(qp + (size_t)qrc*HD_ + 32 + lh*8);

  f32x4 st[18];
  f32x4 zero = {0.f,0.f,0.f,0.f};
  #pragma unroll
  for (int t = 0; t < 18; ++t) st[t] = zero;
  #pragma unroll
  for (int t = 0; t < 18; ++t) {
    int key = t*16 + lr;  int keyc = key < 271 ? key : 271;
    bf16x8 b0 = *(const bf16x8*)(kp + (size_t)keyc*HD_ + lh*8);
    bf16x8 b1 = *(const bf16x8*)(kp + (size_t)keyc*HD_ + 32 + lh*8);
    st[t] = __builtin_amdgcn_mfma_f32_16x16x32_bf16(aq0, b0, st[t], 0, 0, 0);
    st[t] = __builtin_amdgcn_mfma_f32_16x16x32_bf16(aq1, b1, st[t], 0, 0, 0);
  }
  #pragma unroll
  for (int t = 0; t < 18; ++t) {
    int key = t*16 + lr;
    if (key >= SEQ) { st[t][0]=-1e30f; st[t][1]=-1e30f; st[t][2]=-1e30f; st[t][3]=-1e30f; }
  }
  float mr[4], sr[4];
  #pragma unroll
  for (int r = 0; r < 4; ++r) {
    float m = st[0][r];
    #pragma unroll
    for (int t = 1; t < 18; ++t) m = fmaxf(m, st[t][r]);
    m = fmaxf(m, __shfl_xor(m, 1));  m = fmaxf(m, __shfl_xor(m, 2));
    m = fmaxf(m, __shfl_xor(m, 4));  m = fmaxf(m, __shfl_xor(m, 8));
    mr[r] = m;  sr[r] = 0.f;
  }
  #pragma unroll
  for (int t = 0; t < 18; ++t)
    #pragma unroll
    for (int r = 0; r < 4; ++r) {
      float p = __expf(st[t][r] - mr[r]);
      st[t][r] = p;  sr[r] += p;
    }
  #pragma unroll
  for (int r = 0; r < 4; ++r) {
    sr[r] += __shfl_xor(sr[r], 1);  sr[r] += __shfl_xor(sr[r], 2);
    sr[r] += __shfl_xor(sr[r], 4);  sr[r] += __shfl_xor(sr[r], 8);
  }
  #pragma unroll
  for (int t = 0; t < 18; ++t)
    #pragma unroll
    for (int r = 0; r < 4; ++r)
      P[(w*16 + lh*4 + r)*296 + t*16 + lr] = f2bf(st[t][r]);
  __syncthreads();

  f32x4 o[4];
  #pragma unroll
  for (int ni = 0; ni < 4; ++ni) o[ni] = zero;
  #pragma unroll
  for (int ks = 0; ks < 9; ++ks) {
    bf16x8 pa = *(const bf16x8*)&P[(w*16 + lr)*296 + ks*32 + lh*8];
    #pragma unroll
    for (int ni = 0; ni < 4; ++ni) {
      bf16x8 bv_ = *(const bf16x8*)(vp + (size_t)(ni*16 + lr)*VPAD + ks*32 + lh*8);
      o[ni] = __builtin_amdgcn_mfma_f32_16x16x32_bf16(pa, bv_, o[ni], 0, 0, 0);
    }
  }
  #pragma unroll
  for (int r = 0; r < 4; ++r) {
    const int qrow = q0 + w*16 + lh*4 + r;
    if (qrow < SEQ) {
      const float inv = 1.f / sr[r];
      #pragma unroll
      for (int ni = 0; ni < 4; ++ni)
        attn_out[(size_t)(b*SEQ + qrow)*DD + hh*HD_ + ni*16 + lr] = f2bf(o[ni][r] * inv);
    }
  }
}

// ---------------- host ----------------------------------------------------
extern "C" void kernel_launch(void* const* d_in, const int* in_sizes, int n_in,
                              void* d_out, int out_size, void* d_ws, size_t ws_size,
                              hipStream_t stream) {
  (void)in_sizes; (void)n_in; (void)out_size; (void)ws_size;
  const float* hidden   = (const float*)d_in[0];
  const float* cached_h = (const float*)d_in[1];
  const float* cached_q = (const float*)d_in[2];
  const float* cached_k = (const float*)d_in[3];
  const float* cached_v = (const float*)d_in[4];
  const float* ln1_g = (const float*)d_in[5];
  const float* ln1_b = (const float*)d_in[6];
  const float* wq = (const float*)d_in[7];
  const float* bq = (const float*)d_in[8];
  const float* wk = (const float*)d_in[9];
  const float* bk = (const float*)d_in[10];
  const float* wv = (const float*)d_in[11];
  const float* bv = (const float*)d_in[12];
  const float* wo = (const float*)d_in[13];
  const float* bo = (const float*)d_in[14];
  const float* ln2_g = (const float*)d_in[15];
  const float* ln2_b = (const float*)d_in[16];
  const float* w1 = (const float*)d_in[17];
  const float* b1 = (const float*)d_in[18];
  const float* w2 = (const float*)d_in[19];
  const float* b2 = (const float*)d_in[20];
  const float* thr = (const float*)d_in[21];
  float* out = (float*)d_out;

  char* ws = (char*)d_ws;
  size_t off = 0;
  auto alloc = [&](size_t bytes) {
    void* p = ws + off;  off += (bytes + 255) & ~(size_t)255;  return p;
  };
  u16*   wqkvT  = (u16*)alloc(3072ull * 1024 * 2);
  u16*   woT    = (u16*)alloc(1024ull * 1024 * 2);
  u16*   w1T    = (u16*)alloc(4096ull * 1024 * 2);
  u16*   w2T    = (u16*)alloc(1024ull * 4096 * 2);
  float* gate   = (float*)alloc((size_t)MPAD2 * 4);
  float* resid2 = (float*)alloc((size_t)MPAD2 * DD * 4);
  u16*   regA   = (u16*)alloc((size_t)MPAD2 * DD * 2);
  u16 *hln = regA, *attn_o = regA, *ln2out = regA;
  const size_t QKV_B  = (size_t)256 * SPAD * HD_ * 2;
  const size_t VT_B   = (size_t)256 * HD_ * VPAD * 2;
  const size_t PART_B = (size_t)MPAD2 * 1024 * 2;
  const size_t partsOff = 3*QKV_B + VT_B;
  char*  regB   = (char*)alloc(partsOff + 2*PART_B);
  u16*   qbuf   = (u16*)regB;
  u16*   kbuf   = (u16*)(regB + QKV_B);
  u16*   vbuf   = (u16*)(regB + 2*QKV_B);
  u16*   vtb    = (u16*)(regB + 3*QKV_B);
  float* hblend = (float*)(regB + partsOff);
  u16*   mid    = (u16*)regB;
  u16*   parts  = (u16*)(regB + partsOff);

  dim3 blk(256);
  // fused prologue: 3072 transpose blocks + 4112 LN1/gate blocks
  prologue_kernel<<<dim3(3072 + MM), blk, 0, stream>>>(
      wq, wk, wv, wo, w1, w2, wqkvT, woT, w1T, w2T,
      hidden, cached_h, ln1_g, ln1_b, thr, hln, hblend, gate);

  // QKV: grid x=m(33), y=n(24); fused blend epilogue
  gemm_bt<0><<<dim3(33, 24), blk, 0, stream>>>(hln, wqkvT, 1024, 1024, nullptr,
      gate, cached_q, cached_k, cached_v, bq, bk, bv, qbuf, kbuf, vbuf,
      nullptr, nullptr, nullptr, nullptr);

  vtrans_kernel<<<dim3(256, 5), blk, 0, stream>>>(vbuf, vtb);
  attn_kernel<<<dim3(256, 5), blk, 0, stream>>>(qbuf, kbuf, vtb, attn_o);

  // O-proj: resid2 = attn@woT + bo + hblend
  gemm_bt<1><<<dim3(33, 8), blk, 0, stream>>>(attn_o, woT, 1024, 1024, bo,
      nullptr, nullptr, nullptr, nullptr, nullptr, nullptr, nullptr,
      nullptr, nullptr, nullptr, hblend, resid2, nullptr, nullptr);

  ln2_kernel<<<dim3(MM), blk, 0, stream>>>(resid2, ln2_g, ln2_b, ln2out);

  // MLP1: gelu(ln2out @ w1T + b1) -> mid
  gemm_bt<2><<<dim3(33, 32), blk, 0, stream>>>(ln2out, w1T, 1024, 1024, b1,
      nullptr, nullptr, nullptr, nullptr, nullptr, nullptr, nullptr,
      nullptr, nullptr, nullptr, nullptr, nullptr, mid, nullptr);

  // MLP2 split-K=2 (z: kBase = z*2048): bf16 partials
  gemm_bt<3><<<dim3(33, 8, 2), blk, 0, stream>>>(mid, w2T, 4096, 2048, nullptr,
      nullptr, nullptr, nullptr, nullptr, nullptr, nullptr, nullptr,
      nullptr, nullptr, nullptr, nullptr, nullptr, nullptr, parts);

  reduce_mlp2<<<dim3(MM), blk, 0, stream>>>(parts, b2, resid2, out);
}